// Round 13
// baseline (264.335 us; speedup 1.0000x reference)
//
#include <hip/hip_runtime.h>
#include <hip/hip_bf16.h>

// ---------------------------------------------------------------------------
// GCN forward, reassociated; fp8(e4m3) off-chip payloads, bf16 MFMA compute:
//   Xs  = fp8(x)                                   [N,128] fp8 (unscaled)
//   Xp  = fp8( dinv.*(dinv.*Xs_self + sum dinv[s].*Xs[s]) )  (agg128) fp8
//   H1  = fp8( dinv .* relu(Xp@W1 + b1) )          (mgemm1)  [N,256] fp8
//   G   = fp8( dinv .* (H1_self + sum H1[src]) )   (agg256)  [N,256] fp8
//   pool = colsum(relu(G@W2 + b2))                 (mgemm2, fused)
//   out = (pool/N)@Wout + bout
// r13: 4B packed pairs ((dlocal<<17)|src); packed f32x2 accumulation in aggs;
// 128-row GEMM tile (2x MFMA per staged B); single memset.
// r12: alias red over As/Bs; spread pool atomics. r11: LDS/atomic contention.
// r8: don't fuse gather into GEMM. r6: gather traffic-bound. r9: no global
// node-histogram atomics.
// ---------------------------------------------------------------------------

typedef __attribute__((ext_vector_type(8))) short short8;
typedef __attribute__((ext_vector_type(4))) float f32x4;
typedef __attribute__((ext_vector_type(2))) float f32x2;

#define BKT_SHIFT 8
#define BKT_NODES 256
#define BIN_CHUNK 8192
#define CAP 4608   // per-bucket capacity (mean 4096, sigma~64, +8 sigma)
#define PSLOTS 64  // pool accumulation slots (atomic spread)
#define SRC_BITS 17
#define SRC_MASK 0x1FFFFu

__device__ inline unsigned short f2bf(float f) {
    union { float f; unsigned u; } v; v.f = f;
    unsigned r = (v.u + 0x7fff + ((v.u >> 16) & 1)) >> 16;
    return (unsigned short)r;
}

// ------------- fused prep: bin | cvtx | wt1 | wt2 (grid-partitioned) --------
__global__ __launch_bounds__(256) void prep_k(const int* __restrict__ ei,
                                              int* __restrict__ bcur,
                                              unsigned* __restrict__ pairs,
                                              const float* __restrict__ x,
                                              unsigned* __restrict__ Xs,
                                              const float* __restrict__ W1,
                                              unsigned short* __restrict__ Wt1,
                                              const float* __restrict__ W2,
                                              unsigned short* __restrict__ Wt2,
                                              int E, int N, int NB,
                                              int NCHUNK, int NCVT) {
    int b = blockIdx.x;
    int tid = threadIdx.x;
    if (b < NCHUNK) {
        __shared__ int hist[512];
        __shared__ int base[512];
        int chunk0 = b * BIN_CHUNK;
        for (int t = tid; t < NB; t += 256) hist[t] = 0;
        __syncthreads();
#pragma unroll 4
        for (int i = 0; i < BIN_CHUNK / 256; ++i) {
            int e = chunk0 + i * 256 + tid;
            if (e < E) {
                unsigned d = (unsigned)ei[(size_t)E + e];
                if (d < (unsigned)N) atomicAdd(&hist[d >> BKT_SHIFT], 1);
            }
        }
        __syncthreads();
        for (int t = tid; t < NB; t += 256) {
            int c = hist[t];
            base[t] = c ? (t * CAP + atomicAdd(&bcur[t], c)) : 0;
            hist[t] = 0;
        }
        __syncthreads();
#pragma unroll 4
        for (int i = 0; i < BIN_CHUNK / 256; ++i) {
            int e = chunk0 + i * 256 + tid;
            if (e < E) {
                unsigned d = (unsigned)ei[(size_t)E + e];
                unsigned s = (unsigned)ei[e];
                if (d < (unsigned)N) {
                    int bb = d >> BKT_SHIFT;
                    int r = atomicAdd(&hist[bb], 1);
                    unsigned sc = (s < (unsigned)N) ? s : 0u;
                    pairs[base[bb] + r] = ((d & (BKT_NODES - 1)) << SRC_BITS) | sc;
                }
            }
        }
    } else if (b < NCHUNK + NCVT) {
        int idx = (b - NCHUNK) * 256 + tid;
        if (idx < N * 32) {
            float4 v = ((const float4*)x)[idx];
            float a = fminf(fmaxf(v.x, -448.f), 448.f);
            float bb = fminf(fmaxf(v.y, -448.f), 448.f);
            float c = fminf(fmaxf(v.z, -448.f), 448.f);
            float d = fminf(fmaxf(v.w, -448.f), 448.f);
            int p = __builtin_amdgcn_cvt_pk_fp8_f32(a, bb, 0, false);
            p = __builtin_amdgcn_cvt_pk_fp8_f32(c, d, p, true);
            Xs[idx] = (unsigned)p;
        }
    } else if (b < NCHUNK + NCVT + 128) {
        int idx = (b - NCHUNK - NCVT) * 256 + tid;
        int k = idx >> 8, nn = idx & 255;
        Wt1[nn * 128 + k] = f2bf(W1[idx]);
    } else {
        int idx = (b - NCHUNK - NCVT - 128) * 256 + tid;
        int k = idx >> 8, nn = idx & 255;
        Wt2[nn * 256 + k] = f2bf(W2[idx]);
    }
}

// --------- per-bucket: node hist + scan -> off/deg/dinv, csr scatter --------
__global__ __launch_bounds__(512) void scatter_k(const unsigned* __restrict__ pairs,
                                                 const int* __restrict__ bcur,
                                                 int* __restrict__ off,
                                                 int* __restrict__ deg,
                                                 float* __restrict__ dinv,
                                                 int* __restrict__ csr, int N) {
    __shared__ int h[2][256];
    __shared__ int cur[256];
    int b = blockIdx.x, t = threadIdx.x;
    int lo = b << BKT_SHIFT;
    int rs = b * CAP;
    int re = rs + min(bcur[b], CAP);
    if (t < 256) h[0][t] = 0;
    __syncthreads();
    for (int i = rs + t; i < re; i += 512)
        atomicAdd(&h[0][pairs[i] >> SRC_BITS], 1);
    __syncthreads();
    int v = (t < 256) ? h[0][t] : 0;
    int cu = 0;
    for (int o = 1; o < 256; o <<= 1) {
        int val = 0;
        if (t < 256) { val = h[cu][t]; if (t >= o) val += h[cu][t - o]; }
        __syncthreads();
        if (t < 256) h[cu ^ 1][t] = val;
        cu ^= 1;
        __syncthreads();
    }
    if (t < 256) {
        int no = rs + (h[cu][t] - v);
        if (lo + t < N) {
            off[lo + t] = no;
            deg[lo + t] = v;
            dinv[lo + t] = rsqrtf((float)v + 1.0f);
        }
        cur[t] = no;
    }
    __syncthreads();
    for (int i = rs + t; i < re; i += 512) {
        unsigned p = pairs[i];
        int pos = atomicAdd(&cur[p >> SRC_BITS], 1);
        csr[pos] = (int)(p & SRC_MASK);
    }
}

// --------------------- aggregation (one wave per node, unroll 8) ------------
__global__ __launch_bounds__(256) void agg128_k(const unsigned short* __restrict__ X8,
                                                const int* __restrict__ csr,
                                                const int* __restrict__ off,
                                                const int* __restrict__ deg,
                                                const float* __restrict__ dinv,
                                                unsigned short* __restrict__ O8, int n) {
    int w = (blockIdx.x * 256 + threadIdx.x) >> 6;
    int lane = threadIdx.x & 63;
    if (w >= n) return;
    int st = off[w], c = deg[w];
    float di = dinv[w];
    f32x2 sv = __builtin_amdgcn_cvt_pk_f32_fp8((int)X8[(size_t)w * 64 + lane], false);
    f32x2 acc[4];
    acc[0] = di * sv;
    acc[1] = 0.f; acc[2] = 0.f; acc[3] = 0.f;
    int e = 0;
    for (; e + 8 <= c; e += 8) {
        int s[8];
#pragma unroll
        for (int j = 0; j < 8; ++j) s[j] = csr[st + e + j];
        float wd[8];
#pragma unroll
        for (int j = 0; j < 8; ++j) wd[j] = dinv[s[j]];
        unsigned short u[8];
#pragma unroll
        for (int j = 0; j < 8; ++j) u[j] = X8[(size_t)s[j] * 64 + lane];
#pragma unroll
        for (int j = 0; j < 8; ++j) {
            f32x2 f = __builtin_amdgcn_cvt_pk_f32_fp8((int)u[j], false);
            acc[j & 3] += wd[j] * f;
        }
    }
    if (e + 4 <= c) {
        int s[4];
#pragma unroll
        for (int j = 0; j < 4; ++j) s[j] = csr[st + e + j];
        float wd[4];
#pragma unroll
        for (int j = 0; j < 4; ++j) wd[j] = dinv[s[j]];
        unsigned short u[4];
#pragma unroll
        for (int j = 0; j < 4; ++j) u[j] = X8[(size_t)s[j] * 64 + lane];
#pragma unroll
        for (int j = 0; j < 4; ++j) {
            f32x2 f = __builtin_amdgcn_cvt_pk_f32_fp8((int)u[j], false);
            acc[j] += wd[j] * f;
        }
        e += 4;
    }
    for (; e < c; ++e) {
        int s = csr[st + e];
        float wd = dinv[s];
        f32x2 f = __builtin_amdgcn_cvt_pk_f32_fp8((int)X8[(size_t)s * 64 + lane], false);
        acc[0] += wd * f;
    }
    f32x2 tot = (acc[0] + acc[1]) + (acc[2] + acc[3]);
    float ox = fminf(fmaxf(di * tot[0], -448.f), 448.f);
    float oy = fminf(fmaxf(di * tot[1], -448.f), 448.f);
    int pk = __builtin_amdgcn_cvt_pk_fp8_f32(ox, oy, 0, false);
    O8[(size_t)w * 64 + lane] = (unsigned short)(pk & 0xffff);
}

__global__ __launch_bounds__(256) void agg256_k(const unsigned* __restrict__ H8,
                                                const int* __restrict__ csr,
                                                const int* __restrict__ off,
                                                const int* __restrict__ deg,
                                                const float* __restrict__ dinv,
                                                unsigned* __restrict__ O8, int n) {
    int w = (blockIdx.x * 256 + threadIdx.x) >> 6;
    int lane = threadIdx.x & 63;
    if (w >= n) return;
    int st = off[w], c = deg[w];
    float di = dinv[w];
    unsigned su = H8[(size_t)w * 64 + lane];
    f32x2 al[4], ah[4];
    al[0] = __builtin_amdgcn_cvt_pk_f32_fp8((int)su, false);
    ah[0] = __builtin_amdgcn_cvt_pk_f32_fp8((int)su, true);
    al[1] = 0.f; al[2] = 0.f; al[3] = 0.f;
    ah[1] = 0.f; ah[2] = 0.f; ah[3] = 0.f;
    int e = 0;
    for (; e + 8 <= c; e += 8) {
        int s[8];
#pragma unroll
        for (int j = 0; j < 8; ++j) s[j] = csr[st + e + j];
        unsigned u[8];
#pragma unroll
        for (int j = 0; j < 8; ++j) u[j] = H8[(size_t)s[j] * 64 + lane];
#pragma unroll
        for (int j = 0; j < 8; ++j) {
            al[j & 3] += (f32x2)__builtin_amdgcn_cvt_pk_f32_fp8((int)u[j], false);
            ah[j & 3] += (f32x2)__builtin_amdgcn_cvt_pk_f32_fp8((int)u[j], true);
        }
    }
    if (e + 4 <= c) {
        int s[4];
#pragma unroll
        for (int j = 0; j < 4; ++j) s[j] = csr[st + e + j];
        unsigned u[4];
#pragma unroll
        for (int j = 0; j < 4; ++j) u[j] = H8[(size_t)s[j] * 64 + lane];
#pragma unroll
        for (int j = 0; j < 4; ++j) {
            al[j] += (f32x2)__builtin_amdgcn_cvt_pk_f32_fp8((int)u[j], false);
            ah[j] += (f32x2)__builtin_amdgcn_cvt_pk_f32_fp8((int)u[j], true);
        }
        e += 4;
    }
    for (; e < c; ++e) {
        int s = csr[st + e];
        unsigned u = H8[(size_t)s * 64 + lane];
        al[0] += (f32x2)__builtin_amdgcn_cvt_pk_f32_fp8((int)u, false);
        ah[0] += (f32x2)__builtin_amdgcn_cvt_pk_f32_fp8((int)u, true);
    }
    f32x2 L = (al[0] + al[1]) + (al[2] + al[3]);
    f32x2 H = (ah[0] + ah[1]) + (ah[2] + ah[3]);
    float o0 = fminf(fmaxf(di * L[0], -448.f), 448.f);
    float o1 = fminf(fmaxf(di * L[1], -448.f), 448.f);
    float o2 = fminf(fmaxf(di * H[0], -448.f), 448.f);
    float o3 = fminf(fmaxf(di * H[1], -448.f), 448.f);
    int pk = __builtin_amdgcn_cvt_pk_fp8_f32(o0, o1, 0, false);
    pk = __builtin_amdgcn_cvt_pk_fp8_f32(o2, o3, pk, true);
    O8[(size_t)w * 64 + lane] = (unsigned)pk;
}

// ------------------- MFMA bf16 GEMM, fp8 A-operand, 128-row tile ------------
// 128 rows x 256 cols per block; wave w owns rows w*32..w*32+31 (2 frags).
// 32 MFMA : 18 ds_read per kt (vs 16:17 at 64 rows). LDS 30.7KB.
// MODE 2 epilogue: red[16][256] aliases As/Bs; pool atomics spread PSLOTS.
template <int MODE>
__global__ __launch_bounds__(256) void mgemm_k(const unsigned char* __restrict__ A8,
                                               const unsigned short* __restrict__ Bt,
                                               const float* __restrict__ bias,
                                               const float* __restrict__ dinv,
                                               unsigned char* __restrict__ Hout8,
                                               float* __restrict__ pool,
                                               int M, int K) {
    __shared__ __align__(16) char smem[(128 + 256) * 40 * 2];  // As | Bs, 30720B
    short* As = (short*)smem;                  // 128*40
    short* Bs = (short*)(smem + 128 * 40 * 2); // 256*40
    int tid = threadIdx.x;
    int w = tid >> 6, lane = tid & 63, lr = lane >> 4, lc = lane & 15;
    int row0 = blockIdx.x * 128;
    int arow = tid >> 1, ahalf = (tid & 1) * 16;
    f32x4 acc0[16] = {};
    f32x4 acc1[16] = {};

    for (int kt = 0; kt < K; kt += 32) {
        short8 vlo = {}, vhi = {};
        int gr = row0 + arow;
        if (gr < M) {
            uint4 v = *(const uint4*)(A8 + (size_t)gr * K + kt + ahalf);
            f32x2 f0 = __builtin_amdgcn_cvt_pk_f32_fp8((int)v.x, false);
            f32x2 f1 = __builtin_amdgcn_cvt_pk_f32_fp8((int)v.x, true);
            f32x2 f2 = __builtin_amdgcn_cvt_pk_f32_fp8((int)v.y, false);
            f32x2 f3 = __builtin_amdgcn_cvt_pk_f32_fp8((int)v.y, true);
            vlo[0] = (short)f2bf(f0[0]); vlo[1] = (short)f2bf(f0[1]);
            vlo[2] = (short)f2bf(f1[0]); vlo[3] = (short)f2bf(f1[1]);
            vlo[4] = (short)f2bf(f2[0]); vlo[5] = (short)f2bf(f2[1]);
            vlo[6] = (short)f2bf(f3[0]); vlo[7] = (short)f2bf(f3[1]);
            f32x2 g0 = __builtin_amdgcn_cvt_pk_f32_fp8((int)v.z, false);
            f32x2 g1 = __builtin_amdgcn_cvt_pk_f32_fp8((int)v.z, true);
            f32x2 g2 = __builtin_amdgcn_cvt_pk_f32_fp8((int)v.w, false);
            f32x2 g3 = __builtin_amdgcn_cvt_pk_f32_fp8((int)v.w, true);
            vhi[0] = (short)f2bf(g0[0]); vhi[1] = (short)f2bf(g0[1]);
            vhi[2] = (short)f2bf(g1[0]); vhi[3] = (short)f2bf(g1[1]);
            vhi[4] = (short)f2bf(g2[0]); vhi[5] = (short)f2bf(g2[1]);
            vhi[6] = (short)f2bf(g3[0]); vhi[7] = (short)f2bf(g3[1]);
        }
        *(short8*)&As[arow * 40 + ahalf] = vlo;
        *(short8*)&As[arow * 40 + ahalf + 8] = vhi;
#pragma unroll
        for (int l = 0; l < 4; ++l) {
            int f = tid + l * 256;
            int br = f >> 2, bk = (f & 3) * 8;
            short8 vb = *(const short8*)(Bt + (size_t)br * K + kt + bk);
            *(short8*)&Bs[br * 40 + bk] = vb;
        }
        __syncthreads();
        short8 af0 = *(const short8*)&As[(w * 32 + lc) * 40 + lr * 8];
        short8 af1 = *(const short8*)&As[(w * 32 + 16 + lc) * 40 + lr * 8];
#pragma unroll
        for (int f = 0; f < 16; ++f) {
            short8 bf = *(const short8*)&Bs[(f * 16 + lc) * 40 + lr * 8];
            acc0[f] = __builtin_amdgcn_mfma_f32_16x16x32_bf16(af0, bf, acc0[f], 0, 0, 0);
            acc1[f] = __builtin_amdgcn_mfma_f32_16x16x32_bf16(af1, bf, acc1[f], 0, 0, 0);
        }
        __syncthreads();
    }

    float bv[16];
#pragma unroll
    for (int f = 0; f < 16; ++f) bv[f] = bias[f * 16 + lc];

    if (MODE == 1) {
#pragma unroll
        for (int r = 0; r < 4; ++r) {
            int gr = row0 + w * 32 + lr * 4 + r;
            if (gr < M) {
                float dr = dinv[gr];
#pragma unroll
                for (int f = 0; f < 16; ++f) {
                    float v = fminf(dr * fmaxf(acc0[f][r] + bv[f], 0.f), 448.f);
                    int p = __builtin_amdgcn_cvt_pk_fp8_f32(v, v, 0, false);
                    Hout8[(size_t)gr * 256 + f * 16 + lc] = (unsigned char)(p & 0xff);
                }
            }
            int gr1 = gr + 16;
            if (gr1 < M) {
                float dr = dinv[gr1];
#pragma unroll
                for (int f = 0; f < 16; ++f) {
                    float v = fminf(dr * fmaxf(acc1[f][r] + bv[f], 0.f), 448.f);
                    int p = __builtin_amdgcn_cvt_pk_fp8_f32(v, v, 0, false);
                    Hout8[(size_t)gr1 * 256 + f * 16 + lc] = (unsigned char)(p & 0xff);
                }
            }
        }
    } else {
        float (*red)[256] = (float(*)[256])smem;   // alias As/Bs (16KB < 30.7KB)
        float s[16];
#pragma unroll
        for (int f = 0; f < 16; ++f) s[f] = 0.f;
#pragma unroll
        for (int r = 0; r < 4; ++r) {
            int gr = row0 + w * 32 + lr * 4 + r;
            if (gr < M) {
#pragma unroll
                for (int f = 0; f < 16; ++f)
                    s[f] += fmaxf(acc0[f][r] + bv[f], 0.f);
            }
            if (gr + 16 < M) {
#pragma unroll
                for (int f = 0; f < 16; ++f)
                    s[f] += fmaxf(acc1[f][r] + bv[f], 0.f);
            }
        }
#pragma unroll
        for (int f = 0; f < 16; ++f) red[w * 4 + lr][f * 16 + lc] = s[f];
        __syncthreads();
        float t = 0.f;
#pragma unroll
        for (int rr = 0; rr < 16; ++rr) t += red[rr][tid];
        atomicAdd(&pool[(blockIdx.x & (PSLOTS - 1)) * 256 + tid], t);
    }
}

__global__ void final_k(const float* __restrict__ pool, const float* __restrict__ Wout,
                        const float* __restrict__ bout, float* __restrict__ out, float invM) {
    __shared__ float s[256];
    int t = threadIdx.x;
    float acc = 0.f;
    for (int sl = 0; sl < PSLOTS; ++sl) acc += pool[sl * 256 + t];
    s[t] = acc * invM * Wout[t];
    __syncthreads();
    for (int o = 128; o > 0; o >>= 1) {
        if (t < o) s[t] += s[t + o];
        __syncthreads();
    }
    if (t == 0) out[0] = s[0] + bout[0];
}

extern "C" void kernel_launch(void* const* d_in, const int* in_sizes, int n_in,
                              void* d_out, int out_size, void* d_ws, size_t ws_size,
                              hipStream_t stream) {
    const float* x    = (const float*)d_in[0];
    const int*   ei   = (const int*)d_in[1];
    const float* W1   = (const float*)d_in[2];
    const float* b1   = (const float*)d_in[3];
    const float* W2   = (const float*)d_in[4];
    const float* b2   = (const float*)d_in[5];
    const float* Wout = (const float*)d_in[6];
    const float* bout = (const float*)d_in[7];
    float* out = (float*)d_out;

    const int N = in_sizes[0] / 128;       // 100000
    const int E = in_sizes[1] / 2;         // 1600000
    const int NB = (N + BKT_NODES - 1) / BKT_NODES;   // 391 buckets
    const int NCHUNK = (E + BIN_CHUNK - 1) / BIN_CHUNK;
    const int NCVT = (N * 32 + 255) / 256;

    char* p = (char*)d_ws;
    auto carve = [&](size_t bytes) -> void* {
        void* r = (void*)p;
        p += (bytes + 511) & ~(size_t)511;
        return r;
    };
    unsigned*       Xs   = (unsigned*)carve((size_t)N * 128);            // fp8
    unsigned short* Xp   = (unsigned short*)carve((size_t)N * 128);      // fp8
    unsigned char*  H1   = (unsigned char*)carve((size_t)N * 256);       // fp8
    unsigned*       G    = (unsigned*)carve((size_t)N * 256);            // fp8
    unsigned short* Wt1  = (unsigned short*)carve((size_t)128 * 256 * 2);
    unsigned short* Wt2  = (unsigned short*)carve((size_t)256 * 256 * 2);
    float* dinv   = (float*)carve((size_t)N * 4);
    int*   off    = (int*)carve((size_t)N * 4);
    int*   deg    = (int*)carve((size_t)N * 4);
    int*   csr    = (int*)carve((size_t)NB * CAP * 4);
    unsigned* pairs = (unsigned*)carve((size_t)NB * CAP * 4);
    int*   bcur   = (int*)carve((size_t)NB * 4);
    float* pool   = (float*)carve((size_t)PSLOTS * 256 * 4);

    // bcur..pool are contiguous carves: one memset covers both (incl. padding)
    hipMemsetAsync(bcur, 0, (size_t)((char*)pool + PSLOTS * 256 * 4 - (char*)bcur), stream);

    prep_k<<<NCHUNK + NCVT + 128 + 256, 256, 0, stream>>>(
        ei, bcur, pairs, x, Xs, W1, Wt1, W2, Wt2, E, N, NB, NCHUNK, NCVT);
    scatter_k<<<NB, 512, 0, stream>>>(pairs, bcur, off, deg, dinv, csr, N);

    // layer 1
    agg128_k<<<(N + 3) / 4, 256, 0, stream>>>((const unsigned short*)Xs, csr, off, deg, dinv, Xp, N);
    mgemm_k<1><<<(N + 127) / 128, 256, 0, stream>>>(
        (const unsigned char*)Xp, Wt1, b1, dinv, H1, nullptr, N, 128);

    // layer 2
    agg256_k<<<(N + 3) / 4, 256, 0, stream>>>((const unsigned*)H1, csr, off, deg, dinv, G, N);
    mgemm_k<2><<<(N + 127) / 128, 256, 0, stream>>>(
        (const unsigned char*)G, Wt2, b2, nullptr, nullptr, pool, N, 256);

    final_k<<<1, 256, 0, stream>>>(pool, Wout, bout, out, 1.0f / N);
}

// Round 15
// 253.370 us; speedup vs baseline: 1.0433x; 1.0433x over previous
//
#include <hip/hip_runtime.h>
#include <hip/hip_bf16.h>

// ---------------------------------------------------------------------------
// GCN forward, reassociated; fp8(e4m3) activations off-chip, bf16 MFMA:
//   Xs  = fp8(x)                                   [N,128] fp8 (unscaled)
//   Xp  = fp8( dinv.*(dinv.*Xs_self + sum dinv[s].*Xs[s]) )  (agg128) fp8
//   H1  = fp8( dinv .* relu(Xp@W1 + b1) )          (mgemm1)  [N,256] fp8
//   G   = fp8( dinv .* (H1_self + sum H1[src]) )   (agg256)  fp8
//   pool = colsum(relu(G@W2 + b2))                 (mgemm2, fused)
//   out = (pool/N)@Wout + bout
// r14 lesson: fp8 WEIGHTS fail validation (1.1e-3 > 5.6e-4) — weight rounding
// is coherent per output column, doesn't average out. Weights stay bf16.
// r13 keepers: 4B packed pairs; packed f32x2 agg accumulation; single memset.
// r13 revert: 128-row tile (tail imbalance) -> 64-row tile (r12's 260us).
// r12: alias red over As/Bs; spread pool atomics. r8: don't fuse gather into
// GEMM. r6: gather traffic-bound (aggs at floor). r9: no global node-hist.
// ---------------------------------------------------------------------------

typedef __attribute__((ext_vector_type(8))) short short8;
typedef __attribute__((ext_vector_type(4))) float f32x4;
typedef __attribute__((ext_vector_type(2))) float f32x2;

#define BKT_SHIFT 8
#define BKT_NODES 256
#define BIN_CHUNK 8192
#define CAP 4608   // per-bucket capacity (mean 4096, sigma~64, +8 sigma)
#define PSLOTS 64  // pool accumulation slots (atomic spread)
#define SRC_BITS 17
#define SRC_MASK 0x1FFFFu

__device__ inline unsigned short f2bf(float f) {
    union { float f; unsigned u; } v; v.f = f;
    unsigned r = (v.u + 0x7fff + ((v.u >> 16) & 1)) >> 16;
    return (unsigned short)r;
}

// ------------- fused prep: bin | cvtx | wt1 | wt2 (grid-partitioned) --------
__global__ __launch_bounds__(256) void prep_k(const int* __restrict__ ei,
                                              int* __restrict__ bcur,
                                              unsigned* __restrict__ pairs,
                                              const float* __restrict__ x,
                                              unsigned* __restrict__ Xs,
                                              const float* __restrict__ W1,
                                              unsigned short* __restrict__ Wt1,
                                              const float* __restrict__ W2,
                                              unsigned short* __restrict__ Wt2,
                                              int E, int N, int NB,
                                              int NCHUNK, int NCVT) {
    int b = blockIdx.x;
    int tid = threadIdx.x;
    if (b < NCHUNK) {
        __shared__ int hist[512];
        __shared__ int base[512];
        int chunk0 = b * BIN_CHUNK;
        for (int t = tid; t < NB; t += 256) hist[t] = 0;
        __syncthreads();
#pragma unroll 4
        for (int i = 0; i < BIN_CHUNK / 256; ++i) {
            int e = chunk0 + i * 256 + tid;
            if (e < E) {
                unsigned d = (unsigned)ei[(size_t)E + e];
                if (d < (unsigned)N) atomicAdd(&hist[d >> BKT_SHIFT], 1);
            }
        }
        __syncthreads();
        for (int t = tid; t < NB; t += 256) {
            int c = hist[t];
            base[t] = c ? (t * CAP + atomicAdd(&bcur[t], c)) : 0;
            hist[t] = 0;
        }
        __syncthreads();
#pragma unroll 4
        for (int i = 0; i < BIN_CHUNK / 256; ++i) {
            int e = chunk0 + i * 256 + tid;
            if (e < E) {
                unsigned d = (unsigned)ei[(size_t)E + e];
                unsigned s = (unsigned)ei[e];
                if (d < (unsigned)N) {
                    int bb = d >> BKT_SHIFT;
                    int r = atomicAdd(&hist[bb], 1);
                    unsigned sc = (s < (unsigned)N) ? s : 0u;
                    pairs[base[bb] + r] = ((d & (BKT_NODES - 1)) << SRC_BITS) | sc;
                }
            }
        }
    } else if (b < NCHUNK + NCVT) {
        int idx = (b - NCHUNK) * 256 + tid;
        if (idx < N * 32) {
            float4 v = ((const float4*)x)[idx];
            float a = fminf(fmaxf(v.x, -448.f), 448.f);
            float bb = fminf(fmaxf(v.y, -448.f), 448.f);
            float c = fminf(fmaxf(v.z, -448.f), 448.f);
            float d = fminf(fmaxf(v.w, -448.f), 448.f);
            int p = __builtin_amdgcn_cvt_pk_fp8_f32(a, bb, 0, false);
            p = __builtin_amdgcn_cvt_pk_fp8_f32(c, d, p, true);
            Xs[idx] = (unsigned)p;
        }
    } else if (b < NCHUNK + NCVT + 128) {
        // W1[128][256] fp32 -> Wt1[256][128] bf16
        int idx = (b - NCHUNK - NCVT) * 256 + tid;
        int k = idx >> 8, nn = idx & 255;
        Wt1[nn * 128 + k] = f2bf(W1[idx]);
    } else {
        int idx = (b - NCHUNK - NCVT - 128) * 256 + tid;
        int k = idx >> 8, nn = idx & 255;
        Wt2[nn * 256 + k] = f2bf(W2[idx]);
    }
}

// --------- per-bucket: node hist + scan -> off/deg/dinv, csr scatter --------
__global__ __launch_bounds__(512) void scatter_k(const unsigned* __restrict__ pairs,
                                                 const int* __restrict__ bcur,
                                                 int* __restrict__ off,
                                                 int* __restrict__ deg,
                                                 float* __restrict__ dinv,
                                                 int* __restrict__ csr, int N) {
    __shared__ int h[2][256];
    __shared__ int cur[256];
    int b = blockIdx.x, t = threadIdx.x;
    int lo = b << BKT_SHIFT;
    int rs = b * CAP;
    int re = rs + min(bcur[b], CAP);
    if (t < 256) h[0][t] = 0;
    __syncthreads();
    for (int i = rs + t; i < re; i += 512)
        atomicAdd(&h[0][pairs[i] >> SRC_BITS], 1);
    __syncthreads();
    int v = (t < 256) ? h[0][t] : 0;
    int cu = 0;
    for (int o = 1; o < 256; o <<= 1) {
        int val = 0;
        if (t < 256) { val = h[cu][t]; if (t >= o) val += h[cu][t - o]; }
        __syncthreads();
        if (t < 256) h[cu ^ 1][t] = val;
        cu ^= 1;
        __syncthreads();
    }
    if (t < 256) {
        int no = rs + (h[cu][t] - v);
        if (lo + t < N) {
            off[lo + t] = no;
            deg[lo + t] = v;
            dinv[lo + t] = rsqrtf((float)v + 1.0f);
        }
        cur[t] = no;
    }
    __syncthreads();
    for (int i = rs + t; i < re; i += 512) {
        unsigned p = pairs[i];
        int pos = atomicAdd(&cur[p >> SRC_BITS], 1);
        csr[pos] = (int)(p & SRC_MASK);
    }
}

// --------------------- aggregation (one wave per node, unroll 8) ------------
__global__ __launch_bounds__(256) void agg128_k(const unsigned short* __restrict__ X8,
                                                const int* __restrict__ csr,
                                                const int* __restrict__ off,
                                                const int* __restrict__ deg,
                                                const float* __restrict__ dinv,
                                                unsigned short* __restrict__ O8, int n) {
    int w = (blockIdx.x * 256 + threadIdx.x) >> 6;
    int lane = threadIdx.x & 63;
    if (w >= n) return;
    int st = off[w], c = deg[w];
    float di = dinv[w];
    f32x2 sv = __builtin_amdgcn_cvt_pk_f32_fp8((int)X8[(size_t)w * 64 + lane], false);
    f32x2 acc[4];
    acc[0] = di * sv;
    acc[1] = 0.f; acc[2] = 0.f; acc[3] = 0.f;
    int e = 0;
    for (; e + 8 <= c; e += 8) {
        int s[8];
#pragma unroll
        for (int j = 0; j < 8; ++j) s[j] = csr[st + e + j];
        float wd[8];
#pragma unroll
        for (int j = 0; j < 8; ++j) wd[j] = dinv[s[j]];
        unsigned short u[8];
#pragma unroll
        for (int j = 0; j < 8; ++j) u[j] = X8[(size_t)s[j] * 64 + lane];
#pragma unroll
        for (int j = 0; j < 8; ++j) {
            f32x2 f = __builtin_amdgcn_cvt_pk_f32_fp8((int)u[j], false);
            acc[j & 3] += wd[j] * f;
        }
    }
    if (e + 4 <= c) {
        int s[4];
#pragma unroll
        for (int j = 0; j < 4; ++j) s[j] = csr[st + e + j];
        float wd[4];
#pragma unroll
        for (int j = 0; j < 4; ++j) wd[j] = dinv[s[j]];
        unsigned short u[4];
#pragma unroll
        for (int j = 0; j < 4; ++j) u[j] = X8[(size_t)s[j] * 64 + lane];
#pragma unroll
        for (int j = 0; j < 4; ++j) {
            f32x2 f = __builtin_amdgcn_cvt_pk_f32_fp8((int)u[j], false);
            acc[j] += wd[j] * f;
        }
        e += 4;
    }
    for (; e < c; ++e) {
        int s = csr[st + e];
        float wd = dinv[s];
        f32x2 f = __builtin_amdgcn_cvt_pk_f32_fp8((int)X8[(size_t)s * 64 + lane], false);
        acc[0] += wd * f;
    }
    f32x2 tot = (acc[0] + acc[1]) + (acc[2] + acc[3]);
    float ox = fminf(fmaxf(di * tot[0], -448.f), 448.f);
    float oy = fminf(fmaxf(di * tot[1], -448.f), 448.f);
    int pk = __builtin_amdgcn_cvt_pk_fp8_f32(ox, oy, 0, false);
    O8[(size_t)w * 64 + lane] = (unsigned short)(pk & 0xffff);
}

__global__ __launch_bounds__(256) void agg256_k(const unsigned* __restrict__ H8,
                                                const int* __restrict__ csr,
                                                const int* __restrict__ off,
                                                const int* __restrict__ deg,
                                                const float* __restrict__ dinv,
                                                unsigned* __restrict__ O8, int n) {
    int w = (blockIdx.x * 256 + threadIdx.x) >> 6;
    int lane = threadIdx.x & 63;
    if (w >= n) return;
    int st = off[w], c = deg[w];
    float di = dinv[w];
    unsigned su = H8[(size_t)w * 64 + lane];
    f32x2 al[4], ah[4];
    al[0] = __builtin_amdgcn_cvt_pk_f32_fp8((int)su, false);
    ah[0] = __builtin_amdgcn_cvt_pk_f32_fp8((int)su, true);
    al[1] = 0.f; al[2] = 0.f; al[3] = 0.f;
    ah[1] = 0.f; ah[2] = 0.f; ah[3] = 0.f;
    int e = 0;
    for (; e + 8 <= c; e += 8) {
        int s[8];
#pragma unroll
        for (int j = 0; j < 8; ++j) s[j] = csr[st + e + j];
        unsigned u[8];
#pragma unroll
        for (int j = 0; j < 8; ++j) u[j] = H8[(size_t)s[j] * 64 + lane];
#pragma unroll
        for (int j = 0; j < 8; ++j) {
            al[j & 3] += (f32x2)__builtin_amdgcn_cvt_pk_f32_fp8((int)u[j], false);
            ah[j & 3] += (f32x2)__builtin_amdgcn_cvt_pk_f32_fp8((int)u[j], true);
        }
    }
    if (e + 4 <= c) {
        int s[4];
#pragma unroll
        for (int j = 0; j < 4; ++j) s[j] = csr[st + e + j];
        unsigned u[4];
#pragma unroll
        for (int j = 0; j < 4; ++j) u[j] = H8[(size_t)s[j] * 64 + lane];
#pragma unroll
        for (int j = 0; j < 4; ++j) {
            al[j] += (f32x2)__builtin_amdgcn_cvt_pk_f32_fp8((int)u[j], false);
            ah[j] += (f32x2)__builtin_amdgcn_cvt_pk_f32_fp8((int)u[j], true);
        }
        e += 4;
    }
    for (; e < c; ++e) {
        int s = csr[st + e];
        unsigned u = H8[(size_t)s * 64 + lane];
        al[0] += (f32x2)__builtin_amdgcn_cvt_pk_f32_fp8((int)u, false);
        ah[0] += (f32x2)__builtin_amdgcn_cvt_pk_f32_fp8((int)u, true);
    }
    f32x2 L = (al[0] + al[1]) + (al[2] + al[3]);
    f32x2 H = (ah[0] + ah[1]) + (ah[2] + ah[3]);
    float o0 = fminf(fmaxf(di * L[0], -448.f), 448.f);
    float o1 = fminf(fmaxf(di * L[1], -448.f), 448.f);
    float o2 = fminf(fmaxf(di * H[0], -448.f), 448.f);
    float o3 = fminf(fmaxf(di * H[1], -448.f), 448.f);
    int pk = __builtin_amdgcn_cvt_pk_fp8_f32(o0, o1, 0, false);
    pk = __builtin_amdgcn_cvt_pk_fp8_f32(o2, o3, pk, true);
    O8[(size_t)w * 64 + lane] = (unsigned)pk;
}

// ------------------------- MFMA bf16 GEMM, fp8 A-operand --------------------
// 64 rows x 256 cols per block, 4 waves, K_STEP=32. A-staging decodes
// fp8->bf16 into LDS (exact); weights bf16 (r14: fp8 weights fail numerics).
// MODE 2 epilogue: red[16][256] aliases As/Bs; pool atomics spread PSLOTS.
template <int MODE>
__global__ __launch_bounds__(256) void mgemm_k(const unsigned char* __restrict__ A8,
                                               const unsigned short* __restrict__ Bt,
                                               const float* __restrict__ bias,
                                               const float* __restrict__ dinv,
                                               unsigned char* __restrict__ Hout8,
                                               float* __restrict__ pool,
                                               int M, int K) {
    __shared__ __align__(16) char smem[(64 + 256) * 40 * 2];  // As | Bs, 25600B
    short* As = (short*)smem;                 // 64*40
    short* Bs = (short*)(smem + 64 * 40 * 2); // 256*40
    int tid = threadIdx.x;
    int w = tid >> 6, lane = tid & 63, lr = lane >> 4, lc = lane & 15;
    int row0 = blockIdx.x * 64;
    int arow = tid >> 2, akoff = (tid & 3) * 8;
    f32x4 acc[16] = {};

    for (int kt = 0; kt < K; kt += 32) {
        short8 va = {};
        int gr = row0 + arow;
        if (gr < M) {
            uint2 v = *(const uint2*)(A8 + (size_t)gr * K + kt + akoff);
            f32x2 f0 = __builtin_amdgcn_cvt_pk_f32_fp8((int)v.x, false);
            f32x2 f1 = __builtin_amdgcn_cvt_pk_f32_fp8((int)v.x, true);
            f32x2 f2 = __builtin_amdgcn_cvt_pk_f32_fp8((int)v.y, false);
            f32x2 f3 = __builtin_amdgcn_cvt_pk_f32_fp8((int)v.y, true);
            va[0] = (short)f2bf(f0[0]); va[1] = (short)f2bf(f0[1]);
            va[2] = (short)f2bf(f1[0]); va[3] = (short)f2bf(f1[1]);
            va[4] = (short)f2bf(f2[0]); va[5] = (short)f2bf(f2[1]);
            va[6] = (short)f2bf(f3[0]); va[7] = (short)f2bf(f3[1]);
        }
        *(short8*)&As[arow * 40 + akoff] = va;
#pragma unroll
        for (int l = 0; l < 4; ++l) {
            int f = tid + l * 256;
            int br = f >> 2, bk = (f & 3) * 8;
            short8 vb = *(const short8*)(Bt + (size_t)br * K + kt + bk);
            *(short8*)&Bs[br * 40 + bk] = vb;
        }
        __syncthreads();
        short8 af = *(const short8*)&As[(w * 16 + lc) * 40 + lr * 8];
#pragma unroll
        for (int f = 0; f < 16; ++f) {
            short8 bf = *(const short8*)&Bs[(f * 16 + lc) * 40 + lr * 8];
            acc[f] = __builtin_amdgcn_mfma_f32_16x16x32_bf16(af, bf, acc[f], 0, 0, 0);
        }
        __syncthreads();
    }

    float bv[16];
#pragma unroll
    for (int f = 0; f < 16; ++f) bv[f] = bias[f * 16 + lc];

    if (MODE == 1) {
#pragma unroll
        for (int r = 0; r < 4; ++r) {
            int gr = row0 + w * 16 + lr * 4 + r;
            if (gr < M) {
                float dr = dinv[gr];
#pragma unroll
                for (int f = 0; f < 16; ++f) {
                    float v = fminf(dr * fmaxf(acc[f][r] + bv[f], 0.f), 448.f);
                    int p = __builtin_amdgcn_cvt_pk_fp8_f32(v, v, 0, false);
                    Hout8[(size_t)gr * 256 + f * 16 + lc] = (unsigned char)(p & 0xff);
                }
            }
        }
    } else {
        float (*red)[256] = (float(*)[256])smem;   // alias As/Bs (16KB < 25.6KB)
        float s[16];
#pragma unroll
        for (int f = 0; f < 16; ++f) s[f] = 0.f;
#pragma unroll
        for (int r = 0; r < 4; ++r) {
            int gr = row0 + w * 16 + lr * 4 + r;
            if (gr < M) {
#pragma unroll
                for (int f = 0; f < 16; ++f)
                    s[f] += fmaxf(acc[f][r] + bv[f], 0.f);
            }
        }
#pragma unroll
        for (int f = 0; f < 16; ++f) red[w * 4 + lr][f * 16 + lc] = s[f];
        __syncthreads();
        float t = 0.f;
#pragma unroll
        for (int rr = 0; rr < 16; ++rr) t += red[rr][tid];
        atomicAdd(&pool[(blockIdx.x & (PSLOTS - 1)) * 256 + tid], t);
    }
}

__global__ void final_k(const float* __restrict__ pool, const float* __restrict__ Wout,
                        const float* __restrict__ bout, float* __restrict__ out, float invM) {
    __shared__ float s[256];
    int t = threadIdx.x;
    float acc = 0.f;
    for (int sl = 0; sl < PSLOTS; ++sl) acc += pool[sl * 256 + t];
    s[t] = acc * invM * Wout[t];
    __syncthreads();
    for (int o = 128; o > 0; o >>= 1) {
        if (t < o) s[t] += s[t + o];
        __syncthreads();
    }
    if (t == 0) out[0] = s[0] + bout[0];
}

extern "C" void kernel_launch(void* const* d_in, const int* in_sizes, int n_in,
                              void* d_out, int out_size, void* d_ws, size_t ws_size,
                              hipStream_t stream) {
    const float* x    = (const float*)d_in[0];
    const int*   ei   = (const int*)d_in[1];
    const float* W1   = (const float*)d_in[2];
    const float* b1   = (const float*)d_in[3];
    const float* W2   = (const float*)d_in[4];
    const float* b2   = (const float*)d_in[5];
    const float* Wout = (const float*)d_in[6];
    const float* bout = (const float*)d_in[7];
    float* out = (float*)d_out;

    const int N = in_sizes[0] / 128;       // 100000
    const int E = in_sizes[1] / 2;         // 1600000
    const int NB = (N + BKT_NODES - 1) / BKT_NODES;   // 391 buckets
    const int NCHUNK = (E + BIN_CHUNK - 1) / BIN_CHUNK;
    const int NCVT = (N * 32 + 255) / 256;

    char* p = (char*)d_ws;
    auto carve = [&](size_t bytes) -> void* {
        void* r = (void*)p;
        p += (bytes + 511) & ~(size_t)511;
        return r;
    };
    unsigned*       Xs   = (unsigned*)carve((size_t)N * 128);            // fp8
    unsigned short* Xp   = (unsigned short*)carve((size_t)N * 128);      // fp8
    unsigned char*  H1   = (unsigned char*)carve((size_t)N * 256);       // fp8
    unsigned*       G    = (unsigned*)carve((size_t)N * 256);            // fp8
    unsigned short* Wt1  = (unsigned short*)carve((size_t)128 * 256 * 2);
    unsigned short* Wt2  = (unsigned short*)carve((size_t)256 * 256 * 2);
    float* dinv   = (float*)carve((size_t)N * 4);
    int*   off    = (int*)carve((size_t)N * 4);
    int*   deg    = (int*)carve((size_t)N * 4);
    int*   csr    = (int*)carve((size_t)NB * CAP * 4);
    unsigned* pairs = (unsigned*)carve((size_t)NB * CAP * 4);
    int*   bcur   = (int*)carve((size_t)NB * 4);
    float* pool   = (float*)carve((size_t)PSLOTS * 256 * 4);

    // bcur..pool are contiguous carves: one memset covers both (incl. padding)
    hipMemsetAsync(bcur, 0, (size_t)((char*)pool + PSLOTS * 256 * 4 - (char*)bcur), stream);

    prep_k<<<NCHUNK + NCVT + 128 + 256, 256, 0, stream>>>(
        ei, bcur, pairs, x, Xs, W1, Wt1, W2, Wt2, E, N, NB, NCHUNK, NCVT);
    scatter_k<<<NB, 512, 0, stream>>>(pairs, bcur, off, deg, dinv, csr, N);

    // layer 1
    agg128_k<<<(N + 3) / 4, 256, 0, stream>>>((const unsigned short*)Xs, csr, off, deg, dinv, Xp, N);
    mgemm_k<1><<<(N + 63) / 64, 256, 0, stream>>>(
        (const unsigned char*)Xp, Wt1, b1, dinv, H1, nullptr, N, 128);

    // layer 2
    agg256_k<<<(N + 3) / 4, 256, 0, stream>>>((const unsigned*)H1, csr, off, deg, dinv, G, N);
    mgemm_k<2><<<(N + 63) / 64, 256, 0, stream>>>(
        (const unsigned char*)G, Wt2, b2, nullptr, nullptr, pool, N, 256);

    final_k<<<1, 256, 0, stream>>>(pool, Wout, bout, out, 1.0f / N);
}